// Round 9
// baseline (6247.254 us; speedup 1.0000x reference)
//
#include <hip/hip_runtime.h>

#define BATCH    128
#define NPTS     32768
#define HALFN    (NPTS / 2)          // 16384 points per block
#define KOUT     1024
#define NTHREADS 512
#define PPT      (HALFN / NTHREADS)  // 32 points per thread

// Pair handshake mailbox, one 128-B line per block in d_ws.
struct __align__(16) Slot {
    unsigned long long key;   // (val_bits<<32) | (0xffffffff - idx)
    unsigned int       seq;   // last iteration posted
};
#define SLOT_STRIDE 128
#define WS_NEEDED   (256 * SLOT_STRIDE)

// 2 blocks per batch (grid 256 = every CU). Each block owns 16384 points:
// 96 coord VGPRs + temps fits the 128-VGPR grant the allocator gives
// 512-thread blocks (measured rounds 6/7) -> ZERO per-iteration coord
// refetch. Rounds 2-8 were L2-refetch-bound (~13 TB/s of coord remat =
// ~80% of L2 ceiling = the 3.6 ms floor). mindist: 64 KiB static LDS,
// strided b32 (bank-conflict-free, rounds 2-7: conflicts == 0).
// Per-iteration argmax is exchanged between the pair via device-scope
// release/acquire mailboxes in d_ws; pair = (b, b+128) lands on the same
// XCD under %8 round-robin. Safe: all 256 blocks co-resident.
__global__ __launch_bounds__(NTHREADS)
void fps_pair_kernel(const float* __restrict__ x, float* __restrict__ out,
                     char* __restrict__ ws) {
    __shared__ float s_md[HALFN];     // 64 KiB, static
    __shared__ float s_redv[8];
    __shared__ int   s_redi[8];
    __shared__ float s_pt[3];

    const int bid  = blockIdx.x;
    const int b    = bid & (BATCH - 1);
    const int half = bid >> 7;              // 0: pts [0,16384), 1: rest
    const int tid  = threadIdx.x;
    const int base = half * HALFN;

    const float* __restrict__ xb = x + (size_t)b * 3 * NPTS;
    float* __restrict__ ob = out + (size_t)b * 3 * KOUT;

    Slot* myslot = (Slot*)(ws + (size_t)bid * SLOT_STRIDE);
    Slot* paslot = (Slot*)(ws + (size_t)(bid ^ 128) * SLOT_STRIDE);

    // This block's 16384 points, strided (coalesced): n = base + tid + i*512.
    float xs[PPT], ys[PPT], zs[PPT];
#pragma unroll
    for (int i = 0; i < PPT; ++i) {
        const int nl = tid + i * NTHREADS;
        const int n  = base + nl;
        xs[i] = xb[n];
        ys[i] = xb[NPTS + n];
        zs[i] = xb[2 * NPTS + n];
        s_md[nl] = 1e10f;
    }

    // First selected point is global index 0.
    float px = xb[0], py = xb[NPTS], pz = xb[2 * NPTS];
    if (half == 0 && tid == 0) {
        ob[0] = px; ob[KOUT] = py; ob[2 * KOUT] = pz;
    }
    __syncthreads();

    const int lane = tid & 63;
    const int wave = tid >> 6;

    for (int j = 1; j < KOUT; ++j) {
        float best = -1.0f;
        int   bi   = 0x7fffffff;

        // Distance update + first-occurrence argmax over this half.
        // Bit-exact vs reference (verified rounds 2-8, absmax 0):
        //   d = fma(dz,dz, fma(dy,dy, rn(dx*dx)))
#pragma unroll
        for (int i = 0; i < PPT; ++i) {
            const int nl = tid + i * NTHREADS;
            const float dx = __fsub_rn(xs[i], px);
            const float dy = __fsub_rn(ys[i], py);
            const float dz = __fsub_rn(zs[i], pz);
            const float d  = __fmaf_rn(dz, dz,
                              __fmaf_rn(dy, dy,
                                __fmul_rn(dx, dx)));
            const float m  = fminf(s_md[nl], d);
            s_md[nl] = m;
            if (m > best) { best = m; bi = base + nl; }  // i asc -> first occ.
        }

        // Wave butterfly argmax (tie -> smaller index).
#pragma unroll
        for (int s = 1; s < 64; s <<= 1) {
            const float ov = __shfl_xor(best, s, 64);
            const int   oi = __shfl_xor(bi,   s, 64);
            if (ov > best || (ov == best && oi < bi)) { best = ov; bi = oi; }
        }
        if (lane == 0) { s_redv[wave] = best; s_redi[wave] = bi; }
        __syncthreads();

        if (wave == 0) {
            float v  = (lane < 8) ? s_redv[lane] : -1.0f;
            int   vi = (lane < 8) ? s_redi[lane] : 0x7fffffff;
#pragma unroll
            for (int s = 1; s < 8; s <<= 1) {
                const float ov = __shfl_xor(v,  s, 64);
                const int   oi = __shfl_xor(vi, s, 64);
                if (ov > v || (ov == v && oi < vi)) { v = ov; vi = oi; }
            }
            if (lane == 0) {
                // Post local winner; key max == (max val, tie -> min idx).
                // Distances >= 0 so float bit order == value order.
                const unsigned long long key =
                    ((unsigned long long)__float_as_uint(v) << 32) |
                    (unsigned long long)(0xffffffffu - (unsigned)vi);
                __hip_atomic_store(&myslot->key, key,
                                   __ATOMIC_RELAXED, __HIP_MEMORY_SCOPE_AGENT);
                __hip_atomic_store(&myslot->seq, (unsigned)j,
                                   __ATOMIC_RELEASE, __HIP_MEMORY_SCOPE_AGENT);
                while (__hip_atomic_load(&paslot->seq, __ATOMIC_ACQUIRE,
                                         __HIP_MEMORY_SCOPE_AGENT) < (unsigned)j) {}
                const unsigned long long pkey =
                    __hip_atomic_load(&paslot->key,
                                      __ATOMIC_RELAXED, __HIP_MEMORY_SCOPE_AGENT);
                const unsigned long long wkey = (pkey > key) ? pkey : key;
                const int widx = (int)(0xffffffffu - (unsigned)(wkey & 0xffffffffu));
                const float sx = xb[widx];
                const float sy = xb[NPTS + widx];
                const float sz = xb[2 * NPTS + widx];
                s_pt[0] = sx; s_pt[1] = sy; s_pt[2] = sz;
                if (half == 0) {
                    ob[j] = sx; ob[KOUT + j] = sy; ob[2 * KOUT + j] = sz;
                }
            }
        }
        __syncthreads();
        px = s_pt[0]; py = s_pt[1]; pz = s_pt[2];
    }
}

// Emergency fallback (ws too small): proven single-block variant (round 6).
__global__ __launch_bounds__(NTHREADS)
void fps_single_kernel(const float* __restrict__ x, float* __restrict__ out) {
    __shared__ float s_md[NPTS];      // 128 KiB, static
    __shared__ float s_redv[8];
    __shared__ int   s_redi[8];
    __shared__ float s_pt[3];

    const int b   = blockIdx.x;
    const int tid = threadIdx.x;
    const float* __restrict__ xb = x + (size_t)b * 3 * NPTS;
    float* __restrict__ ob = out + (size_t)b * 3 * KOUT;
#define SPPT (NPTS / NTHREADS)
    float xs[SPPT], ys[SPPT], zs[SPPT];
#pragma unroll
    for (int i = 0; i < SPPT; ++i) {
        const int n = tid + i * NTHREADS;
        xs[i] = xb[n]; ys[i] = xb[NPTS + n]; zs[i] = xb[2 * NPTS + n];
        s_md[n] = 1e10f;
    }
    float px = xb[0], py = xb[NPTS], pz = xb[2 * NPTS];
    if (tid == 0) { ob[0] = px; ob[KOUT] = py; ob[2 * KOUT] = pz; }
    __syncthreads();
    const int lane = tid & 63, wave = tid >> 6;
    for (int j = 1; j < KOUT; ++j) {
        float best = -1.0f; int bi = 0x7fffffff;
#pragma unroll
        for (int i = 0; i < SPPT; ++i) {
            const int n = tid + i * NTHREADS;
            const float dx = __fsub_rn(xs[i], px);
            const float dy = __fsub_rn(ys[i], py);
            const float dz = __fsub_rn(zs[i], pz);
            const float d  = __fmaf_rn(dz, dz, __fmaf_rn(dy, dy, __fmul_rn(dx, dx)));
            const float m  = fminf(s_md[n], d);
            s_md[n] = m;
            if (m > best) { best = m; bi = n; }
        }
#pragma unroll
        for (int s = 1; s < 64; s <<= 1) {
            const float ov = __shfl_xor(best, s, 64);
            const int   oi = __shfl_xor(bi,   s, 64);
            if (ov > best || (ov == best && oi < bi)) { best = ov; bi = oi; }
        }
        if (lane == 0) { s_redv[wave] = best; s_redi[wave] = bi; }
        __syncthreads();
        if (wave == 0) {
            float v  = (lane < 8) ? s_redv[lane] : -1.0f;
            int   vi = (lane < 8) ? s_redi[lane] : 0x7fffffff;
#pragma unroll
            for (int s = 1; s < 8; s <<= 1) {
                const float ov = __shfl_xor(v,  s, 64);
                const int   oi = __shfl_xor(vi, s, 64);
                if (ov > v || (ov == v && oi < vi)) { v = ov; vi = oi; }
            }
            if (lane == 0) {
                const float sx = xb[vi], sy = xb[NPTS + vi], sz = xb[2 * NPTS + vi];
                s_pt[0] = sx; s_pt[1] = sy; s_pt[2] = sz;
                ob[j] = sx; ob[KOUT + j] = sy; ob[2 * KOUT + j] = sz;
            }
        }
        __syncthreads();
        px = s_pt[0]; py = s_pt[1]; pz = s_pt[2];
    }
}

extern "C" void kernel_launch(void* const* d_in, const int* in_sizes, int n_in,
                              void* d_out, int out_size, void* d_ws, size_t ws_size,
                              hipStream_t stream) {
    const float* x = (const float*)d_in[0];
    float* out = (float*)d_out;
    if (ws_size >= WS_NEEDED) {
        // Zero the mailboxes every launch (graph-capturable, stream-ordered).
        hipMemsetAsync(d_ws, 0, WS_NEEDED, stream);
        fps_pair_kernel<<<2 * BATCH, NTHREADS, 0, stream>>>(x, out, (char*)d_ws);
    } else {
        fps_single_kernel<<<BATCH, NTHREADS, 0, stream>>>(x, out);
    }
}